// Round 10
// baseline (344.531 us; speedup 1.0000x reference)
//
#include <hip/hip_runtime.h>
#include <hip/hip_bf16.h>
#include <math.h>

typedef unsigned short u16;
typedef __attribute__((ext_vector_type(8))) short short8;
typedef __attribute__((ext_vector_type(4))) float f32x4;

#define NTOK 8192
#define DMODEL 1024
#define FDIM 4096
#define NEXP 8
#define CAP 1536

__device__ __forceinline__ u16 f2bf(float f) {
  __hip_bfloat16 b = __float2bfloat16(f);
  u16 u;
  __builtin_memcpy(&u, &b, 2);
  return u;
}

// branchless exact-erf GELU (Abramowitz-Stegun 7.1.26, |err| <= 1.5e-7)
__device__ __forceinline__ float gelu_exact(float v) {
  float x = v * 0.70710678118654752f;
  float ax = fabsf(x);
  float t = __builtin_amdgcn_rcpf(1.0f + 0.3275911f * ax);
  float p =
      t * (0.254829592f +
           t * (-0.284496736f +
                t * (1.421413741f + t * (-1.453152027f + t * 1.061405429f))));
  float er = 1.0f - p * __expf(-ax * ax);
  er = copysignf(er, x);
  return 0.5f * v * (1.0f + er);
}

// async global->LDS DMA, 16B/lane. LDS dest = wave-uniform base + lane*16;
// global source address is per-lane (enables gathered staging).
__device__ __forceinline__ void gload_lds16(const u16* g, u16* l) {
  __builtin_amdgcn_global_load_lds(
      (const __attribute__((address_space(1))) void*)g,
      (__attribute__((address_space(3))) void*)l, 16, 0, 0);
}

// ===== 128x128 fp32 -> bf16 transpose via chunk-XOR 32KB LDS, 256 thr ========
// input tile rows r0..r0+128 (stride Cin), cols c0..c0+128;
// output op[(c0+c)*ostride + r0+r]  (transposed, row-major, stride ostride).
__device__ __forceinline__ void trans128(const float* __restrict__ ip,
                                         u16* __restrict__ op, int Cin,
                                         int ostride, int r0, int c0,
                                         char* lds, int tid) {
  int w = tid >> 5, l = tid & 31;  // 8 rows/pass x 32 col-groups(4 cols)
#pragma unroll
  for (int i = 0; i < 16; i++) {
    int row = i * 8 + w;
    float4 v = *(const float4*)(ip + (size_t)(r0 + row) * Cin + c0 + l * 4);
    uint2 d;
    d.x = (unsigned)f2bf(v.x) | ((unsigned)f2bf(v.y) << 16);
    d.y = (unsigned)f2bf(v.z) | ((unsigned)f2bf(v.w) << 16);
    int ch = (l >> 1) ^ ((row >> 3) & 7);  // chunk = col>>3, XOR-swizzled
    *(uint2*)(lds + row * 256 + ch * 16 + (l & 1) * 8) = d;
  }
  __syncthreads();
#pragma unroll
  for (int p = 0; p < 2; p++) {
    int c = ((tid >> 4) + p * 16) * 4;  // out-row group (4 cols of input)
    int rb = (tid & 15) * 8;
    short8 s0, s1, s2, s3;
#pragma unroll
    for (int j = 0; j < 8; j++) {
      int r = rb + j;
      int ch = (c >> 3) ^ ((r >> 3) & 7);
      uint2 d = *(const uint2*)(lds + r * 256 + ch * 16 + (c & 7) * 2);
      s0[j] = (short)(d.x & 0xffff);
      s1[j] = (short)(d.x >> 16);
      s2[j] = (short)(d.y & 0xffff);
      s3[j] = (short)(d.y >> 16);
    }
    u16* ob = op + (size_t)(c0 + c) * ostride + r0 + rb;
    *(short8*)(ob) = s0;
    *(short8*)(ob + ostride) = s1;
    *(short8*)(ob + 2 * (size_t)ostride) = s2;
    *(short8*)(ob + 3 * (size_t)ostride) = s3;
  }
}

// ===== D1: router (even blocks) || w1 transpose (odd blocks) =================
// w1t has no routing dependency -> its 201MB of HBM overlaps the router pass.
__global__ __launch_bounds__(256) void router_w1t_kernel(
    const float* __restrict__ x, const float* __restrict__ rw,
    const float* __restrict__ w1, int* __restrict__ chosen_e,
    float* __restrict__ chosen_p, u16* __restrict__ w1t) {
  __shared__ __align__(16) char lds[32768];
  int bid = blockIdx.x, tid = threadIdx.x;
  if (bid & 1) {  // w1 [D][F] -> w1t [F][D]; 256 tiles/expert
    int idx = bid >> 1;
    int e = idx >> 8, rem = idx & 255;
    int r0 = (rem >> 5) * 128, c0 = (rem & 31) * 128;
    trans128(w1 + (size_t)e * DMODEL * FDIM, w1t + (size_t)e * DMODEL * FDIM,
             FDIM, DMODEL, r0, c0, lds, tid);
    return;
  }
  int tok = ((bid >> 1) * 256 + tid) >> 6;
  int lane = tid & 63;
  const float4* xp = (const float4*)(x + (size_t)tok * DMODEL) + lane * 4;
  float4 x0 = xp[0], x1 = xp[1], x2 = xp[2], x3 = xp[3];
  float l[8];
#pragma unroll
  for (int e = 0; e < 8; e++) {
    const float4* wp = (const float4*)(rw + (size_t)e * DMODEL) + lane * 4;
    float4 w0 = wp[0], w1v = wp[1], w2v = wp[2], w3 = wp[3];
    float s = x0.x * w0.x + x0.y * w0.y + x0.z * w0.z + x0.w * w0.w;
    s += x1.x * w1v.x + x1.y * w1v.y + x1.z * w1v.z + x1.w * w1v.w;
    s += x2.x * w2v.x + x2.y * w2v.y + x2.z * w2v.z + x2.w * w2v.w;
    s += x3.x * w3.x + x3.y * w3.y + x3.z * w3.z + x3.w * w3.w;
    l[e] = s;
  }
#pragma unroll
  for (int off = 32; off > 0; off >>= 1) {
#pragma unroll
    for (int e = 0; e < 8; e++) l[e] += __shfl_xor(l[e], off, 64);
  }
  if (lane == 0) {
    float best = l[0];
    int am = 0;
#pragma unroll
    for (int e = 1; e < 8; e++)
      if (l[e] > best) { best = l[e]; am = e; }
    float denom = 0.f;
#pragma unroll
    for (int e = 0; e < 8; e++) denom += expf(l[e] - best);
    chosen_e[tok] = am;
    chosen_p[tok] = 1.0f / denom;
  }
}

// ===== D2: scan (block 0) || x fp32->bf16 cast (blocks 1..1024) ==============
__global__ __launch_bounds__(1024) void cast_scan_kernel(
    const float* __restrict__ x, u16* __restrict__ xbf,
    const int* __restrict__ chosen_e, int* __restrict__ tok_of_slot,
    int* __restrict__ counts, float* __restrict__ out) {
  int bid = blockIdx.x, tid = threadIdx.x;
  if (bid == 0) {
    if (tid < 512) {
      int w = tid >> 6, lane = tid & 63;
      unsigned long long ltmask =
          (lane == 63) ? ~0ull >> 1 : (1ull << lane) - 1ull;
      int cnt = 0;
      for (int c = 0; c < NTOK / 64; c++) {
        int i = c * 64 + lane;
        int e = chosen_e[i];
        unsigned long long bal = __ballot(e == w);
        if (e == w) {
          int p = cnt + __popcll(bal & ltmask);
          if (p < CAP) {
            tok_of_slot[w * CAP + p] = i;
          } else {  // dropped token: its out row must be zero (no memset)
            float4 z = make_float4(0.f, 0.f, 0.f, 0.f);
            float* orow = out + (size_t)i * DMODEL;
            for (int d = 0; d < DMODEL; d += 4) *(float4*)(orow + d) = z;
          }
        }
        cnt += __popcll(bal);
      }
      for (int p = cnt + lane; p < CAP; p += 64) tok_of_slot[w * CAP + p] = -1;
      if (lane == 0) counts[w] = cnt < CAP ? cnt : CAP;
    }
    return;
  }
  size_t base = (size_t)(bid - 1) * 8192 + tid * 8;
  float4 v0 = *(const float4*)(x + base);
  float4 v1 = *(const float4*)(x + base + 4);
  short8 sv;
  sv[0] = (short)f2bf(v0.x); sv[1] = (short)f2bf(v0.y);
  sv[2] = (short)f2bf(v0.z); sv[3] = (short)f2bf(v0.w);
  sv[4] = (short)f2bf(v1.x); sv[5] = (short)f2bf(v1.y);
  sv[6] = (short)f2bf(v1.z); sv[7] = (short)f2bf(v1.w);
  *(short8*)(xbf + base) = sv;
}

// ====== 128x128 BK=32 double-buffered 2-phase mainloop (m97 structure) =======
// 256 thr = 4 waves 2M x 2N (per-wave 64x64, acc[4][4]). LDS 32KB dbuf.
template <int KD>
__device__ __forceinline__ void mainloop_db(const u16* pa0, const u16* pa1,
                                            const u16* pb0, const u16* pb1,
                                            u16* smem, f32x4 (&acc)[4][4],
                                            int tid) {
  int wid = tid >> 6, lane = tid & 63;
  int wm = (wid >> 1) * 64, wn = (wid & 1) * 64;
  int fr = lane & 15, fk = (lane >> 4) * 8;
  int aro = (wm + fr) * 32 + fk;
  int bro = 4096 + (wn + fr) * 32 + fk;
  gload_lds16(pa0, smem + tid * 8);
  gload_lds16(pa1, smem + 2048 + tid * 8);
  gload_lds16(pb0, smem + 4096 + tid * 8);
  gload_lds16(pb1, smem + 6144 + tid * 8);
  __syncthreads();
  int cur = 0;
#pragma unroll 1
  for (int t = 0; t < KD / 32; ++t) {
    const u16* cb = smem + cur * 8192;
    u16* nb = smem + (cur ^ 1) * 8192;
    if (t + 1 < KD / 32) {
      int k = (t + 1) * 32;
      gload_lds16(pa0 + k, nb + tid * 8);
      gload_lds16(pa1 + k, nb + 2048 + tid * 8);
      gload_lds16(pb0 + k, nb + 4096 + tid * 8);
      gload_lds16(pb1 + k, nb + 6144 + tid * 8);
    }
    short8 av[4], bv[4];
#pragma unroll
    for (int m = 0; m < 4; m++) av[m] = *(const short8*)(cb + aro + m * 512);
#pragma unroll
    for (int n = 0; n < 4; n++) bv[n] = *(const short8*)(cb + bro + n * 512);
#pragma unroll
    for (int m = 0; m < 4; m++)
#pragma unroll
      for (int n = 0; n < 4; n++)
        acc[m][n] = __builtin_amdgcn_mfma_f32_16x16x32_bf16(av[m], bv[n],
                                                            acc[m][n], 0, 0, 0);
    __syncthreads();
    cur ^= 1;
  }
}

// ===== D3: gemm1 (3072 logical blocks) || w2 transpose (2048 blocks) =========
// interleaved 2:3 so trans blocks fill gemm1's idle HBM/issue slots; gemm2
// (next dispatch) sees completed w2t via same-stream ordering.
// mode 0: full interleaved; mode 1: trans-only grid; mode 2: gemm-only (e0).
template <int NX, int NY>
__global__ __launch_bounds__(256) void gemm1_kernel(
    const u16* __restrict__ xbf, const u16* __restrict__ w1tB,
    const int* __restrict__ tok_of_slot, const int* __restrict__ counts,
    u16* __restrict__ hB, const float* __restrict__ b1,
    const float* __restrict__ w2, u16* __restrict__ w2t, int mode, int e0,
    long long hStrideE) {
  __shared__ __align__(16) u16 smem[16384];  // 32KB: trans / dbuf / C-image
  int tid = threadIdx.x;
  int gid = 0, tIdx = -1, gridz = 1;
  if (mode == 0) {
    int r = blockIdx.x % 5;
    if (r < 2) tIdx = (blockIdx.x / 5) * 2 + r;
    else gid = (blockIdx.x / 5) * 3 + (r - 2);
    gridz = NEXP;
  } else if (mode == 1) {
    tIdx = blockIdx.x;
  } else {
    gid = blockIdx.x;
  }
  if (tIdx >= 0) {  // w2 [F][D] -> w2t [D][F]; 256 tiles/expert
    int e = tIdx >> 8, rem = tIdx & 255;
    int r0 = (rem >> 3) * 128, c0 = (rem & 7) * 128;
    trans128(w2 + (size_t)e * DMODEL * FDIM, w2t + (size_t)e * DMODEL * FDIM,
             DMODEL, FDIM, r0, c0, (char*)smem, tid);
    return;
  }
  // XCD-heuristic swizzle on logical gemm id
  int nwg = NX * NY * gridz;
  int swz = (gid & 7) * (nwg >> 3) + (gid >> 3);
  int bx = swz % NX;
  int rem2 = swz / NX;
  int by = rem2 % NY;
  int bz = rem2 / NY;
  int e = e0 + bz;
  int m0 = by * 128, n0 = bx * 128;
  if (m0 >= counts[e]) return;  // slots [counts,CAP) are never gathered
  const u16* Bg = w1tB + (size_t)e * FDIM * DMODEL;
  u16* H = hB + (size_t)bz * hStrideE;
  const float* b1g = b1 + (size_t)e * FDIM;
  int r2 = tid >> 2, c8 = (tid & 3) * 8;
  int t0 = tok_of_slot[e * CAP + m0 + r2];
  t0 &= ~(t0 >> 31);
  int t1 = tok_of_slot[e * CAP + m0 + 64 + r2];
  t1 &= ~(t1 >> 31);
  const u16* pa0 = xbf + (size_t)t0 * DMODEL + c8;
  const u16* pa1 = xbf + (size_t)t1 * DMODEL + c8;
  const u16* pb0 = Bg + (size_t)(n0 + r2) * DMODEL + c8;
  const u16* pb1 = pb0 + (size_t)64 * DMODEL;
  f32x4 acc[4][4] = {};
  mainloop_db<DMODEL>(pa0, pa1, pb0, pb1, smem, acc, tid);

  // epilogue: bias + exact GELU -> swizzled LDS image -> coalesced H stores
  int wid = tid >> 6, lane = tid & 63;
  int wm = (wid >> 1) * 64, wn = (wid & 1) * 64;
  int fr = lane & 15, fq = lane >> 4;
  float bias[4];
#pragma unroll
  for (int n = 0; n < 4; n++) bias[n] = b1g[n0 + wn + n * 16 + fr];
#pragma unroll
  for (int m = 0; m < 4; m++) {
#pragma unroll
    for (int n = 0; n < 4; n++) {
      int colL = wn + n * 16 + fr;  // 0..127
#pragma unroll
      for (int j = 0; j < 4; j++) {
        int rL = wm + m * 16 + fq * 4 + j;  // 0..127
        float v = gelu_exact(acc[m][n][j] + bias[n]);
        int ch = (colL >> 3) ^ ((rL >> 2) & 7);
        smem[rL * 128 + ch * 8 + (colL & 7)] = f2bf(v);
      }
    }
  }
  __syncthreads();
#pragma unroll
  for (int p = 0; p < 8; p++) {
    int idx = p * 256 + tid;
    int rr = idx >> 4, cch = idx & 15;
    int ch = cch ^ ((rr >> 2) & 7);
    short8 v = *(const short8*)(smem + rr * 128 + ch * 8);
    *(short8*)(H + (size_t)(m0 + rr) * FDIM + n0 + cch * 8) = v;
  }
}

// ---------------- XCD-aware bijective tile swizzle (nwg % 8 == 0) ------------
template <int NX, int NY>
__device__ __forceinline__ void tile_coords(int& bx, int& by, int& bz) {
  int flat = blockIdx.x + NX * (blockIdx.y + NY * blockIdx.z);
  int nwg = NX * NY * (int)gridDim.z;
  int swz = (flat & 7) * (nwg >> 3) + (flat >> 3);
  bx = swz % NX;
  int rem = swz / NX;
  by = rem % NY;
  bz = rem / NY;
}

// ---------------- D4: GEMM2 h @ w2t^T + b2, fused gather+scale into out ------
template <int NX, int NY>
__global__ __launch_bounds__(256) void gemm2_kernel(
    const u16* __restrict__ hB, const u16* __restrict__ w2tB,
    float* __restrict__ out, const float* __restrict__ b2,
    const int* __restrict__ tok_of_slot, const int* __restrict__ counts,
    const float* __restrict__ chosen_p, int e0, long long hStrideE) {
  __shared__ __align__(16) u16 smem[16384];  // 32KB dbuf
  int bx, by, bz;
  tile_coords<NX, NY>(bx, by, bz);
  int e = e0 + bz;
  int m0 = by * 128, n0 = bx * 128;
  if (m0 >= counts[e]) return;  // same exit condition as gemm1
  const u16* Ag = hB + (size_t)bz * hStrideE;
  const u16* Bg = w2tB + (size_t)e * DMODEL * FDIM;
  const float* b2g = b2 + (size_t)e * DMODEL;
  int tid = threadIdx.x;
  int r2 = tid >> 2, c8 = (tid & 3) * 8;
  const u16* pa0 = Ag + (size_t)(m0 + r2) * FDIM + c8;
  const u16* pa1 = pa0 + (size_t)64 * FDIM;
  const u16* pb0 = Bg + (size_t)(n0 + r2) * FDIM + c8;
  const u16* pb1 = pb0 + (size_t)64 * FDIM;
  f32x4 acc[4][4] = {};
  mainloop_db<FDIM>(pa0, pa1, pb0, pb1, smem, acc, tid);

  int wid = tid >> 6, lane = tid & 63;
  int wm = (wid >> 1) * 64, wn = (wid & 1) * 64;
  int fr = lane & 15, fq = lane >> 4;
  float bias[4];
#pragma unroll
  for (int n = 0; n < 4; n++) bias[n] = b2g[n0 + wn + n * 16 + fr];
#pragma unroll
  for (int m = 0; m < 4; m++) {
#pragma unroll
    for (int j = 0; j < 4; j++) {
      int rL = wm + m * 16 + fq * 4 + j;
      int tk = tok_of_slot[e * CAP + m0 + rL];
      if (tk >= 0) {
        float sc = chosen_p[tk];
#pragma unroll
        for (int n = 0; n < 4; n++) {
          int colL = wn + n * 16 + fr;
          out[(size_t)tk * DMODEL + n0 + colL] = (acc[m][n][j] + bias[n]) * sc;
        }
      }
    }
  }
}

extern "C" void kernel_launch(void* const* d_in, const int* in_sizes, int n_in,
                              void* d_out, int out_size, void* d_ws,
                              size_t ws_size, hipStream_t stream) {
  const float* x = (const float*)d_in[0];
  const float* rw = (const float*)d_in[1];
  const float* w1 = (const float*)d_in[2];
  const float* b1 = (const float*)d_in[3];
  const float* w2 = (const float*)d_in[4];
  const float* b2 = (const float*)d_in[5];
  float* out = (float*)d_out;

  char* ws = (char*)d_ws;
  size_t off = 0;
  auto alloc = [&](size_t bytes) -> void* {
    void* p = ws + off;
    off = (off + bytes + 255) & ~(size_t)255;
    return p;
  };
  int* chosen_e = (int*)alloc((size_t)NTOK * 4);
  float* chosen_p = (float*)alloc((size_t)NTOK * 4);
  int* tok_of_slot = (int*)alloc((size_t)NEXP * CAP * 4);
  int* counts = (int*)alloc(NEXP * 4);
  u16* xbf = (u16*)alloc((size_t)NTOK * DMODEL * 2);
  u16* w1t = (u16*)alloc((size_t)NEXP * DMODEL * FDIM * 2);
  u16* w2t = (u16*)alloc((size_t)NEXP * DMODEL * FDIM * 2);
  size_t hFull = (size_t)NEXP * CAP * FDIM * 2;
  size_t hLoop = (size_t)CAP * FDIM * 2;
  bool full = (off + hFull) <= ws_size;
  u16* h = (u16*)alloc(full ? hFull : hLoop);

  static_assert(CAP % 128 == 0 && FDIM % 128 == 0 && DMODEL % 128 == 0, "");

  // D1: router || w1 transpose (2048 + 2048 blocks, odd/even interleave)
  router_w1t_kernel<<<4096, 256, 0, stream>>>(x, rw, w1, chosen_e, chosen_p,
                                              w1t);
  // D2: scan || x cast (1 + 1024 blocks)
  cast_scan_kernel<<<1025, 1024, 0, stream>>>(x, xbf, chosen_e, tok_of_slot,
                                              counts, out);

  if (full) {
    // D3: gemm1 (3072) || w2 transpose (2048), 2:3 interleave
    gemm1_kernel<FDIM / 128, CAP / 128><<<5120, 256, 0, stream>>>(
        xbf, w1t, tok_of_slot, counts, h, b1, w2, w2t, 0, 0,
        (long long)CAP * FDIM);
    // D4: gemm2
    gemm2_kernel<DMODEL / 128, CAP / 128>
        <<<dim3(DMODEL / 128, CAP / 128, NEXP), 256, 0, stream>>>(
            h, w2t, out, b2, tok_of_slot, counts, chosen_p, 0,
            (long long)CAP * FDIM);
  } else {
    // fallback: w2 transpose standalone, then per-expert gemms
    gemm1_kernel<FDIM / 128, CAP / 128><<<2048, 256, 0, stream>>>(
        xbf, w1t, tok_of_slot, counts, h, b1, w2, w2t, 1, 0, 0);
    for (int e = 0; e < NEXP; e++) {
      gemm1_kernel<FDIM / 128, CAP / 128>
          <<<(FDIM / 128) * (CAP / 128), 256, 0, stream>>>(
              xbf, w1t, tok_of_slot, counts, h, b1, w2, w2t, 2, e, 0);
      gemm2_kernel<DMODEL / 128, CAP / 128>
          <<<dim3(DMODEL / 128, CAP / 128, 1), 256, 0, stream>>>(
              h, w2t, out, b2, tok_of_slot, counts, chosen_p, e, 0);
    }
  }
  (void)in_sizes;
  (void)n_in;
  (void)ws_size;
}

// Round 11
// 320.868 us; speedup vs baseline: 1.0737x; 1.0737x over previous
//
#include <hip/hip_runtime.h>
#include <hip/hip_bf16.h>
#include <math.h>

typedef unsigned short u16;
typedef __attribute__((ext_vector_type(8))) short short8;
typedef __attribute__((ext_vector_type(4))) float f32x4;

#define NTOK 8192
#define DMODEL 1024
#define FDIM 4096
#define NEXP 8
#define CAP 1536

__device__ __forceinline__ u16 f2bf(float f) {
  __hip_bfloat16 b = __float2bfloat16(f);
  u16 u;
  __builtin_memcpy(&u, &b, 2);
  return u;
}

// branchless exact-erf GELU (Abramowitz-Stegun 7.1.26, |err| <= 1.5e-7)
__device__ __forceinline__ float gelu_exact(float v) {
  float x = v * 0.70710678118654752f;
  float ax = fabsf(x);
  float t = __builtin_amdgcn_rcpf(1.0f + 0.3275911f * ax);
  float p =
      t * (0.254829592f +
           t * (-0.284496736f +
                t * (1.421413741f + t * (-1.453152027f + t * 1.061405429f))));
  float er = 1.0f - p * __expf(-ax * ax);
  er = copysignf(er, x);
  return 0.5f * v * (1.0f + er);
}

// async global->LDS DMA, 16B/lane. LDS dest = wave-uniform base + lane*16;
// global source address is per-lane (enables gathered staging).
__device__ __forceinline__ void gload_lds16(const u16* g, u16* l) {
  __builtin_amdgcn_global_load_lds(
      (const __attribute__((address_space(1))) void*)g,
      (__attribute__((address_space(3))) void*)l, 16, 0, 0);
}

// ===== K1: x fp32->bf16 cast + router ========================================
// blocks [0,4096): x cast; [4096,6144): router (4 tokens/block, 1 wave/token)
__global__ __launch_bounds__(256) void router_cast_kernel(
    const float* __restrict__ x, const float* __restrict__ rw,
    u16* __restrict__ xbf, int* __restrict__ chosen_e,
    float* __restrict__ chosen_p) {
  int b = blockIdx.x, tid = threadIdx.x;
  if (b < 4096) {
    size_t base = (size_t)b * 2048 + tid * 8;
    float4 v0 = *(const float4*)(x + base);
    float4 v1 = *(const float4*)(x + base + 4);
    short8 sv;
    sv[0] = (short)f2bf(v0.x); sv[1] = (short)f2bf(v0.y);
    sv[2] = (short)f2bf(v0.z); sv[3] = (short)f2bf(v0.w);
    sv[4] = (short)f2bf(v1.x); sv[5] = (short)f2bf(v1.y);
    sv[6] = (short)f2bf(v1.z); sv[7] = (short)f2bf(v1.w);
    *(short8*)(xbf + base) = sv;
  } else {
    int tok = ((b - 4096) * 256 + tid) >> 6;
    int lane = tid & 63;
    const float4* xp = (const float4*)(x + (size_t)tok * DMODEL) + lane * 4;
    float4 x0 = xp[0], x1 = xp[1], x2 = xp[2], x3 = xp[3];
    float l[8];
#pragma unroll
    for (int e = 0; e < 8; e++) {
      const float4* wp = (const float4*)(rw + (size_t)e * DMODEL) + lane * 4;
      float4 w0 = wp[0], w1v = wp[1], w2v = wp[2], w3 = wp[3];
      float s = x0.x * w0.x + x0.y * w0.y + x0.z * w0.z + x0.w * w0.w;
      s += x1.x * w1v.x + x1.y * w1v.y + x1.z * w1v.z + x1.w * w1v.w;
      s += x2.x * w2v.x + x2.y * w2v.y + x2.z * w2v.z + x2.w * w2v.w;
      s += x3.x * w3.x + x3.y * w3.y + x3.z * w3.z + x3.w * w3.w;
      l[e] = s;
    }
#pragma unroll
    for (int off = 32; off > 0; off >>= 1) {
#pragma unroll
      for (int e = 0; e < 8; e++) l[e] += __shfl_xor(l[e], off, 64);
    }
    if (lane == 0) {
      float best = l[0];
      int am = 0;
#pragma unroll
      for (int e = 1; e < 8; e++)
        if (l[e] > best) { best = l[e]; am = e; }
      float denom = 0.f;
#pragma unroll
      for (int e = 0; e < 8; e++) denom += expf(l[e] - best);
      chosen_e[tok] = am;
      chosen_p[tok] = 1.0f / denom;
    }
  }
}

// 256x256 fp32->bf16 transpose tile through swizzled LDS, 1024 threads.
__device__ __forceinline__ void trans256(const float* __restrict__ ip,
                                         u16* __restrict__ op, int Rin,
                                         int Cin, int r0, int c0, char* lds,
                                         int tid) {
  int w = tid >> 6, l = tid & 63;
#pragma unroll
  for (int i = 0; i < 16; i++) {
    int row = w * 16 + i;
    float4 v = *(const float4*)(ip + (size_t)(r0 + row) * Cin + c0 + l * 4);
    uint2 d;
    d.x = (unsigned)f2bf(v.x) | ((unsigned)f2bf(v.y) << 16);
    d.y = (unsigned)f2bf(v.z) | ((unsigned)f2bf(v.w) << 16);
    int ch = (l >> 1) ^ ((row >> 3) & 7);
    *(uint2*)(lds + row * 512 + ch * 16 + (l & 1) * 8) = d;
  }
  __syncthreads();
#pragma unroll
  for (int p = 0; p < 2; p++) {
    int c = ((tid >> 5) + p * 32) * 4;
    int rb = (tid & 31) * 8;
    short8 s0, s1, s2, s3;
#pragma unroll
    for (int j = 0; j < 8; j++) {
      int r = rb + j;
      int ch = (c >> 3) ^ ((r >> 3) & 7);
      uint2 d = *(const uint2*)(lds + r * 512 + ch * 16 + (c & 7) * 2);
      s0[j] = (short)(d.x & 0xffff);
      s1[j] = (short)(d.x >> 16);
      s2[j] = (short)(d.y & 0xffff);
      s3[j] = (short)(d.y >> 16);
    }
    u16* ob = op + (size_t)(c0 + c) * Rin + r0 + rb;
    *(short8*)(ob) = s0;
    *(short8*)(ob + (size_t)Rin) = s1;
    *(short8*)(ob + 2 * (size_t)Rin) = s2;
    *(short8*)(ob + 3 * (size_t)Rin) = s3;
  }
}

// ===== K2: scan (block 0) + w1/w2 transpose (blocks 1..1024) ================
__global__ __launch_bounds__(1024, 1) void wtrans_kernel(
    const float* __restrict__ w1, const float* __restrict__ w2,
    u16* __restrict__ w1t, u16* __restrict__ w2t,
    const int* __restrict__ chosen_e, int* __restrict__ tok_of_slot,
    int* __restrict__ counts, float* __restrict__ out) {
  extern __shared__ char lds[];
  int b = blockIdx.x, tid = threadIdx.x;
  if (b == 0) {
    if (tid < 512) {
      int w = tid >> 6, lane = tid & 63;
      unsigned long long ltmask =
          (lane == 63) ? ~0ull >> 1 : (1ull << lane) - 1ull;
      int cnt = 0;
      for (int c = 0; c < NTOK / 64; c++) {
        int i = c * 64 + lane;
        int e = chosen_e[i];
        unsigned long long bal = __ballot(e == w);
        if (e == w) {
          int p = cnt + __popcll(bal & ltmask);
          if (p < CAP) {
            tok_of_slot[w * CAP + p] = i;
          } else {  // dropped token: its out row must be zero (no memset)
            float4 z = make_float4(0.f, 0.f, 0.f, 0.f);
            float* orow = out + (size_t)i * DMODEL;
            for (int d = 0; d < DMODEL; d += 4) *(float4*)(orow + d) = z;
          }
        }
        cnt += __popcll(bal);
      }
      for (int p = cnt + lane; p < CAP; p += 64) tok_of_slot[w * CAP + p] = -1;
      if (lane == 0) counts[w] = cnt < CAP ? cnt : CAP;
    }
  } else if (b < 513) {
    int idx = b - 1;
    int e = idx >> 6, rem = idx & 63;  // D/256=4 x F/256=16 tiles
    int r0 = (rem >> 4) * 256, c0 = (rem & 15) * 256;
    trans256(w1 + (size_t)e * DMODEL * FDIM, w1t + (size_t)e * DMODEL * FDIM,
             DMODEL, FDIM, r0, c0, lds, tid);
  } else {
    int idx = b - 513;
    int e = idx >> 6, rem = idx & 63;  // F/256=16 x D/256=4 tiles
    int r0 = (rem >> 2) * 256, c0 = (rem & 3) * 256;
    trans256(w2 + (size_t)e * DMODEL * FDIM, w2t + (size_t)e * DMODEL * FDIM,
             FDIM, DMODEL, r0, c0, lds, tid);
  }
}

// ---------------- XCD-aware bijective tile swizzle (nwg % 8 == 0) ------------
template <int NX, int NY>
__device__ __forceinline__ void tile_coords(int& bx, int& by, int& bz) {
  int flat = blockIdx.x + NX * (blockIdx.y + NY * blockIdx.z);
  int nwg = NX * NY * (int)gridDim.z;
  int swz = (flat & 7) * (nwg >> 3) + (flat >> 3);
  bx = swz % NX;
  int rem = swz / NX;
  by = rem % NY;
  bz = rem / NY;
}

// ====== 128x128 BK=32 double-buffered 2-phase mainloop (m97 structure) =======
// 256 thr = 4 waves 2M x 2N (per-wave 64x64, acc[4][4]). LDS 32KB dbuf.
template <int KD>
__device__ __forceinline__ void mainloop_db(const u16* pa0, const u16* pa1,
                                            const u16* pb0, const u16* pb1,
                                            u16* smem, f32x4 (&acc)[4][4],
                                            int tid) {
  int wid = tid >> 6, lane = tid & 63;
  int wm = (wid >> 1) * 64, wn = (wid & 1) * 64;
  int fr = lane & 15, fk = (lane >> 4) * 8;
  int aro = (wm + fr) * 32 + fk;
  int bro = 4096 + (wn + fr) * 32 + fk;
  gload_lds16(pa0, smem + tid * 8);
  gload_lds16(pa1, smem + 2048 + tid * 8);
  gload_lds16(pb0, smem + 4096 + tid * 8);
  gload_lds16(pb1, smem + 6144 + tid * 8);
  __syncthreads();
  int cur = 0;
#pragma unroll 1
  for (int t = 0; t < KD / 32; ++t) {
    const u16* cb = smem + cur * 8192;
    u16* nb = smem + (cur ^ 1) * 8192;
    if (t + 1 < KD / 32) {
      int k = (t + 1) * 32;
      gload_lds16(pa0 + k, nb + tid * 8);
      gload_lds16(pa1 + k, nb + 2048 + tid * 8);
      gload_lds16(pb0 + k, nb + 4096 + tid * 8);
      gload_lds16(pb1 + k, nb + 6144 + tid * 8);
    }
    short8 av[4], bv[4];
#pragma unroll
    for (int m = 0; m < 4; m++) av[m] = *(const short8*)(cb + aro + m * 512);
#pragma unroll
    for (int n = 0; n < 4; n++) bv[n] = *(const short8*)(cb + bro + n * 512);
#pragma unroll
    for (int m = 0; m < 4; m++)
#pragma unroll
      for (int n = 0; n < 4; n++)
        acc[m][n] = __builtin_amdgcn_mfma_f32_16x16x32_bf16(av[m], bv[n],
                                                            acc[m][n], 0, 0, 0);
    __syncthreads();
    cur ^= 1;
  }
}

// ------- GEMM1: 128x128 tile (m97 geometry), gather(xbf) @ w1t^T -> GELU -----
// 2048 active blocks (8/CU, multi-round residency for TLP latency hiding).
// Epilogue: bias+GELU -> swizzled 128x128 bf16 LDS image -> coalesced stores.
template <int NX, int NY>
__global__ __launch_bounds__(256) void gemm1_kernel(
    const u16* __restrict__ xbf, const u16* __restrict__ w1tB,
    const int* __restrict__ tok_of_slot, const int* __restrict__ counts,
    u16* __restrict__ hB, const float* __restrict__ b1, int e0,
    long long hStrideE) {
  __shared__ __align__(16) u16 smem[16384];  // 32KB: dbuf, then C-image
  int bx, by, bz;
  tile_coords<NX, NY>(bx, by, bz);
  int e = e0 + bz;
  int m0 = by * 128, n0 = bx * 128;
  if (m0 >= counts[e]) return;  // slots [counts,CAP) are never gathered
  const u16* Bg = w1tB + (size_t)e * FDIM * DMODEL;
  u16* H = hB + (size_t)bz * hStrideE;
  const float* b1g = b1 + (size_t)e * FDIM;
  int tid = threadIdx.x;
  int r2 = tid >> 2, c8 = (tid & 3) * 8;
  int t0 = tok_of_slot[e * CAP + m0 + r2];
  t0 &= ~(t0 >> 31);
  int t1 = tok_of_slot[e * CAP + m0 + 64 + r2];
  t1 &= ~(t1 >> 31);
  const u16* pa0 = xbf + (size_t)t0 * DMODEL + c8;
  const u16* pa1 = xbf + (size_t)t1 * DMODEL + c8;
  const u16* pb0 = Bg + (size_t)(n0 + r2) * DMODEL + c8;
  const u16* pb1 = pb0 + (size_t)64 * DMODEL;
  f32x4 acc[4][4] = {};
  mainloop_db<DMODEL>(pa0, pa1, pb0, pb1, smem, acc, tid);

  // epilogue: bias + exact GELU -> swizzled LDS image -> coalesced H stores
  int wid = tid >> 6, lane = tid & 63;
  int wm = (wid >> 1) * 64, wn = (wid & 1) * 64;
  int fr = lane & 15, fq = lane >> 4;
  float bias[4];
#pragma unroll
  for (int n = 0; n < 4; n++) bias[n] = b1g[n0 + wn + n * 16 + fr];
#pragma unroll
  for (int m = 0; m < 4; m++) {
#pragma unroll
    for (int n = 0; n < 4; n++) {
      int colL = wn + n * 16 + fr;  // 0..127
#pragma unroll
      for (int j = 0; j < 4; j++) {
        int rL = wm + m * 16 + fq * 4 + j;  // 0..127
        float v = gelu_exact(acc[m][n][j] + bias[n]);
        int ch = (colL >> 3) ^ ((rL >> 2) & 7);
        smem[rL * 128 + ch * 8 + (colL & 7)] = f2bf(v);
      }
    }
  }
  __syncthreads();
#pragma unroll
  for (int p = 0; p < 8; p++) {
    int idx = p * 256 + tid;
    int rr = idx >> 4, cch = idx & 15;
    int ch = cch ^ ((rr >> 2) & 7);
    short8 v = *(const short8*)(smem + rr * 128 + ch * 8);
    *(short8*)(H + (size_t)(m0 + rr) * FDIM + n0 + cch * 8) = v;
  }
}

// ---------------- GEMM2: h @ w2t^T + b2, fused gather+scale into out ---------
template <int NX, int NY>
__global__ __launch_bounds__(256) void gemm2_kernel(
    const u16* __restrict__ hB, const u16* __restrict__ w2tB,
    float* __restrict__ out, const float* __restrict__ b2,
    const int* __restrict__ tok_of_slot, const int* __restrict__ counts,
    const float* __restrict__ chosen_p, int e0, long long hStrideE) {
  __shared__ __align__(16) u16 smem[16384];  // 32KB dbuf
  int bx, by, bz;
  tile_coords<NX, NY>(bx, by, bz);
  int e = e0 + bz;
  int m0 = by * 128, n0 = bx * 128;
  if (m0 >= counts[e]) return;  // same exit condition as gemm1
  const u16* Ag = hB + (size_t)bz * hStrideE;
  const u16* Bg = w2tB + (size_t)e * DMODEL * FDIM;
  const float* b2g = b2 + (size_t)e * DMODEL;
  int tid = threadIdx.x;
  int r2 = tid >> 2, c8 = (tid & 3) * 8;
  const u16* pa0 = Ag + (size_t)(m0 + r2) * FDIM + c8;
  const u16* pa1 = pa0 + (size_t)64 * FDIM;
  const u16* pb0 = Bg + (size_t)(n0 + r2) * FDIM + c8;
  const u16* pb1 = pb0 + (size_t)64 * FDIM;
  f32x4 acc[4][4] = {};
  mainloop_db<FDIM>(pa0, pa1, pb0, pb1, smem, acc, tid);

  int wid = tid >> 6, lane = tid & 63;
  int wm = (wid >> 1) * 64, wn = (wid & 1) * 64;
  int fr = lane & 15, fq = lane >> 4;
  float bias[4];
#pragma unroll
  for (int n = 0; n < 4; n++) bias[n] = b2g[n0 + wn + n * 16 + fr];
#pragma unroll
  for (int m = 0; m < 4; m++) {
#pragma unroll
    for (int j = 0; j < 4; j++) {
      int rL = wm + m * 16 + fq * 4 + j;
      int tk = tok_of_slot[e * CAP + m0 + rL];
      if (tk >= 0) {
        float sc = chosen_p[tk];
#pragma unroll
        for (int n = 0; n < 4; n++) {
          int colL = wn + n * 16 + fr;
          out[(size_t)tk * DMODEL + n0 + colL] = (acc[m][n][j] + bias[n]) * sc;
        }
      }
    }
  }
}

extern "C" void kernel_launch(void* const* d_in, const int* in_sizes, int n_in,
                              void* d_out, int out_size, void* d_ws,
                              size_t ws_size, hipStream_t stream) {
  const float* x = (const float*)d_in[0];
  const float* rw = (const float*)d_in[1];
  const float* w1 = (const float*)d_in[2];
  const float* b1 = (const float*)d_in[3];
  const float* w2 = (const float*)d_in[4];
  const float* b2 = (const float*)d_in[5];
  float* out = (float*)d_out;

  char* ws = (char*)d_ws;
  size_t off = 0;
  auto alloc = [&](size_t bytes) -> void* {
    void* p = ws + off;
    off = (off + bytes + 255) & ~(size_t)255;
    return p;
  };
  int* chosen_e = (int*)alloc((size_t)NTOK * 4);
  float* chosen_p = (float*)alloc((size_t)NTOK * 4);
  int* tok_of_slot = (int*)alloc((size_t)NEXP * CAP * 4);
  int* counts = (int*)alloc(NEXP * 4);
  u16* xbf = (u16*)alloc((size_t)NTOK * DMODEL * 2);
  u16* w1t = (u16*)alloc((size_t)NEXP * DMODEL * FDIM * 2);
  u16* w2t = (u16*)alloc((size_t)NEXP * DMODEL * FDIM * 2);
  size_t hFull = (size_t)NEXP * CAP * FDIM * 2;
  size_t hLoop = (size_t)CAP * FDIM * 2;
  bool full = (off + hFull) <= ws_size;
  u16* h = (u16*)alloc(full ? hFull : hLoop);

  static_assert(CAP % 128 == 0 && FDIM % 128 == 0 && DMODEL % 128 == 0, "");
  const int TLDS = 131072;
  hipFuncSetAttribute((const void*)wtrans_kernel,
                      hipFuncAttributeMaxDynamicSharedMemorySize, TLDS);

  router_cast_kernel<<<4096 + NTOK / 4, 256, 0, stream>>>(x, rw, xbf, chosen_e,
                                                          chosen_p);
  wtrans_kernel<<<1025, 1024, TLDS, stream>>>(w1, w2, w1t, w2t, chosen_e,
                                              tok_of_slot, counts, out);

  if (full) {
    gemm1_kernel<FDIM / 128, CAP / 128>
        <<<dim3(FDIM / 128, CAP / 128, NEXP), 256, 0, stream>>>(
            xbf, w1t, tok_of_slot, counts, h, b1, 0, (long long)CAP * FDIM);
    gemm2_kernel<DMODEL / 128, CAP / 128>
        <<<dim3(DMODEL / 128, CAP / 128, NEXP), 256, 0, stream>>>(
            h, w2t, out, b2, tok_of_slot, counts, chosen_p, 0,
            (long long)CAP * FDIM);
  } else {
    for (int e = 0; e < NEXP; e++) {
      gemm1_kernel<FDIM / 128, CAP / 128>
          <<<dim3(FDIM / 128, CAP / 128, 1), 256, 0, stream>>>(
              xbf, w1t, tok_of_slot, counts, h, b1, e, 0);
      gemm2_kernel<DMODEL / 128, CAP / 128>
          <<<dim3(DMODEL / 128, CAP / 128, 1), 256, 0, stream>>>(
              h, w2t, out, b2, tok_of_slot, counts, chosen_p, e, 0);
    }
  }
  (void)in_sizes;
  (void)n_in;
  (void)ws_size;
}